// Round 6
// baseline (3803.519 us; speedup 1.0000x reference)
//
#include <hip/hip_runtime.h>
#include <math.h>

// LSTM encoder: B=32, S=512, E=512, H=1024, G=4H=4096.
// Round 6: latency pack for the recurrent scan.
//   - 128 WGs x 1024 thr (8 hidden units/WG): half the barrier participants
//   - fan-out barrier: grp(16x8) -> root -> finishing leader writes 16 go
//     words; each WG polls only its group's go line (<=8 pollers/line,
//     vs 256 pollers on one root line before)
//   - xg prefetched one step ahead (HBM latency off the critical path)
//   - coherence scheme unchanged (validated r4/r5): first-touch ring,
//     write-through h stores, all-relaxed atomics, XCD-aware J0 swizzle

#define B_ 32
#define S_ 512
#define E_ 512
#define H_ 1024
#define G_ 4096
#define NWG 128
#define RTHR 1024
#define BH_ (B_ * H_)

typedef _Float16 f16x8 __attribute__((ext_vector_type(8)));
typedef float f32x4 __attribute__((ext_vector_type(4)));

__device__ __forceinline__ float sigmoidf_(float x) {
  return 1.0f / (1.0f + __expf(-x));
}
__device__ __forceinline__ float tanhf_(float x) {
  return 1.0f - 2.0f / (__expf(2.0f * x) + 1.0f);
}

// ---------------- one-time: Whh f32[1024][4096] -> Wt f16[4096][1024] ----------------
__global__ __launch_bounds__(256) void wt_kernel(
    const float* __restrict__ Whh, _Float16* __restrict__ Wt)
{
  __shared__ float Lt[64][65];
  const int c0 = blockIdx.x * 64;
  const int k0 = blockIdx.y * 64;
  const int tid = threadIdx.x;
  const int colL = tid & 63;
  const int rq = tid >> 6;
#pragma unroll 4
  for (int p = 0; p < 16; ++p) {
    int r = p * 4 + rq;
    Lt[colL][r] = Whh[(size_t)(k0 + r) * G_ + c0 + colL];
  }
  __syncthreads();
  const int col = tid >> 2;
  const int kq = (tid & 3) * 16;
  _Float16 tmp[16];
#pragma unroll
  for (int i = 0; i < 16; ++i) tmp[i] = (_Float16)Lt[col][kq + i];
  *(f16x8*)(Wt + (size_t)(c0 + col) * H_ + k0 + kq)     = *(f16x8*)&tmp[0];
  *(f16x8*)(Wt + (size_t)(c0 + col) * H_ + k0 + kq + 8) = *(f16x8*)&tmp[8];
}

// ---------------- Phase A: x-gates GEMM (f32, unchanged) ----------------
__global__ __launch_bounds__(256) void xgates_gemm(
    const int* __restrict__ src, const float* __restrict__ emb,
    const float* __restrict__ Wih, const float* __restrict__ bih,
    const float* __restrict__ bhh, float* __restrict__ xg, int t0)
{
  __shared__ float As[16][132];
  __shared__ float Bs[16][132];
  __shared__ int rowOff[128];

  const int tid = threadIdx.x;
  const int row0 = blockIdx.y * 128;
  const int col0 = blockIdx.x * 128;

  if (tid < 128) {
    int r = row0 + tid;
    int t = t0 + (r >> 5);
    int b = r & 31;
    rowOff[tid] = src[b * S_ + t];
  }
  __syncthreads();

  const int tx = tid & 15, ty = tid >> 4;
  float acc[8][8];
#pragma unroll
  for (int i = 0; i < 8; ++i)
#pragma unroll
    for (int j = 0; j < 8; ++j) acc[i][j] = 0.f;

  const int arl = tid >> 2;
  const int akq = (tid & 3) * 4;
  const int bkr = tid >> 4;
  const int bc  = (tid & 15) * 4;

  for (int k0 = 0; k0 < E_; k0 += 16) {
#pragma unroll
    for (int p = 0; p < 2; ++p) {
      int rl = arl + p * 64;
      float4 v = *(const float4*)(emb + (size_t)rowOff[rl] * E_ + k0 + akq);
      As[akq + 0][rl] = v.x;
      As[akq + 1][rl] = v.y;
      As[akq + 2][rl] = v.z;
      As[akq + 3][rl] = v.w;
    }
#pragma unroll
    for (int p = 0; p < 2; ++p) {
      int c = bc + p * 64;
      *(float4*)&Bs[bkr][c] =
          *(const float4*)(Wih + (size_t)(k0 + bkr) * G_ + col0 + c);
    }
    __syncthreads();
#pragma unroll
    for (int k = 0; k < 16; ++k) {
      float av[8], bv[8];
      *(float4*)&av[0] = *(const float4*)&As[k][ty * 8];
      *(float4*)&av[4] = *(const float4*)&As[k][ty * 8 + 4];
      *(float4*)&bv[0] = *(const float4*)&Bs[k][tx * 4];
      *(float4*)&bv[4] = *(const float4*)&Bs[k][tx * 4 + 64];
#pragma unroll
      for (int i = 0; i < 8; ++i)
#pragma unroll
        for (int j = 0; j < 8; ++j) acc[i][j] = fmaf(av[i], bv[j], acc[i][j]);
    }
    __syncthreads();
  }

  const int ca = col0 + tx * 4;
  const int cb = ca + 64;
  float4 b1 = *(const float4*)(bih + ca);
  float4 b2 = *(const float4*)(bhh + ca);
  float4 b3 = *(const float4*)(bih + cb);
  float4 b4 = *(const float4*)(bhh + cb);
  float4 biasA = make_float4(b1.x + b2.x, b1.y + b2.y, b1.z + b2.z, b1.w + b2.w);
  float4 biasB = make_float4(b3.x + b4.x, b3.y + b4.y, b3.z + b4.z, b3.w + b4.w);
#pragma unroll
  for (int i = 0; i < 8; ++i) {
    int r = row0 + ty * 8 + i;
    float* dst = xg + (size_t)r * G_;
    *(float4*)(dst + ca) = make_float4(acc[i][0] + biasA.x, acc[i][1] + biasA.y,
                                       acc[i][2] + biasA.z, acc[i][3] + biasA.w);
    *(float4*)(dst + cb) = make_float4(acc[i][4] + biasB.x, acc[i][5] + biasB.y,
                                       acc[i][6] + biasB.z, acc[i][7] + biasB.w);
  }
}

// ---------------- Phase R: persistent MFMA recurrent kernel ----------------
// 128 WGs x 1024 thr. WG owns units J0..J0+7 -> 32 gate cols.
// D[32 b x 32 c] = h[32 x 1024] * Wslice[1024 x 32]; 128 MFMA/WG/step.
// Wave w: colpair cp=w&1 (cols cp*16..+16), K range kq=w>>1 (128 wide).
__global__ __launch_bounds__(RTHR) void lstm_mfma(
    const _Float16* __restrict__ Wt, const float* __restrict__ xg,
    unsigned short* hring, float* cbuf, unsigned* root, unsigned* grp,
    unsigned* go, float* out, int t0, int nt)
{
  __shared__ float red[8 * 32 * 37];   // [kq][row][col] stride-37: 37888 B

  const int wg = blockIdx.x;
  const int tid = threadIdx.x;
  // XCD swizzle: 16 WGs per XCD cover 128 contiguous hidden units
  const int J0 = 8 * ((wg & 7) * 16 + (wg >> 3));

  const int wave = tid >> 6;
  const int lane = tid & 63;
  const int lrow = lane & 15;
  const int lhi  = lane >> 4;
  const int cp   = wave & 1;
  const int kq   = wave >> 1;          // 0..7
  const int Kw   = kq * 128;
  const int c    = cp * 16 + lrow;     // col within 32: gate = c>>3, unit = c&7
  const int gcol = (c >> 3) * H_ + J0 + (c & 7);

  // W fragments persistent in registers (16 VGPRs/lane)
  f16x8 bf[4];
#pragma unroll
  for (int s = 0; s < 4; ++s)
    bf[s] = *(const f16x8*)(Wt + (size_t)gcol * H_ + Kw + s * 32 + lhi * 8);

  const int bq = tid >> 3, uq = tid & 7;   // epilogue mapping (tid<256)
  float cstate = 0.f;
  if (tid < 256) cstate = cbuf[(size_t)bq * H_ + J0 + uq];

  // xg for step t0 preloaded (pipeline depth 1)
  float xv0 = 0.f, xv1 = 0.f, xv2 = 0.f, xv3 = 0.f;
  if (tid < 256) {
    const float* xp = xg + (size_t)bq * G_ + J0 + uq;
    xv0 = xp[0 * H_]; xv1 = xp[1 * H_]; xv2 = xp[2 * H_]; xv3 = xp[3 * H_];
  }

  for (int t = t0; t < t0 + nt; ++t) {
    const int lt = t - t0;
    const _Float16* hrd = (const _Float16*)hring + (size_t)lt * BH_;   // first touch
    unsigned short* hwr = hring + (size_t)((lt == nt - 1) ? 0 : lt + 1) * BH_;

    f32x4 acc0 = {0.f, 0.f, 0.f, 0.f};
    f32x4 acc1 = {0.f, 0.f, 0.f, 0.f};
#pragma unroll
    for (int s = 0; s < 4; ++s) {
      f16x8 a0 = *(const f16x8*)(hrd + (size_t)lrow * H_ + Kw + s * 32 + lhi * 8);
      f16x8 a1 = *(const f16x8*)(hrd + (size_t)(16 + lrow) * H_ + Kw + s * 32 + lhi * 8);
      acc0 = __builtin_amdgcn_mfma_f32_16x16x32_f16(a0, bf[s], acc0, 0, 0, 0);
      acc1 = __builtin_amdgcn_mfma_f32_16x16x32_f16(a1, bf[s], acc1, 0, 0, 0);
    }

    // prefetch NEXT step's xg: issues now, consumed after next barrier
    float xn0 = 0.f, xn1 = 0.f, xn2 = 0.f, xn3 = 0.f;
    if (tid < 256) {
      int nlt = (lt == nt - 1) ? lt : lt + 1;
      const float* xp = xg + ((size_t)nlt * B_ + bq) * G_ + J0 + uq;
      xn0 = xp[0 * H_]; xn1 = xp[1 * H_]; xn2 = xp[2 * H_]; xn3 = xp[3 * H_];
    }

    // D layout: col = lane&15 (=lrow), row within tile = lhi*4 + r
#pragma unroll
    for (int r = 0; r < 4; ++r) {
      red[(kq * 32 + lhi * 4 + r) * 37 + c]      = acc0[r];
      red[(kq * 32 + 16 + lhi * 4 + r) * 37 + c] = acc1[r];
    }
    __syncthreads();

    if (tid < 256) {
      float g0 = xv0, g1 = xv1, g2 = xv2, g3 = xv3;
#pragma unroll
      for (int k8 = 0; k8 < 8; ++k8) {
        const float* rp = red + (k8 * 32 + bq) * 37 + uq;
        g0 += rp[0];
        g1 += rp[8];
        g2 += rp[16];
        g3 += rp[24];
      }
      float ig = sigmoidf_(g0);
      float fg = sigmoidf_(g1);
      float gg = tanhf_(g2);
      float og = sigmoidf_(g3);
      cstate = fg * cstate + ig * gg;
      float hval = og * tanhf_(cstate);
      out[((size_t)bq * S_ + t) * H_ + J0 + uq] = hval;   // f32, pre-quantization
      _Float16 hf = (_Float16)hval;
      unsigned short hb;
      __builtin_memcpy(&hb, &hf, 2);
      __hip_atomic_store(hwr + (size_t)bq * H_ + J0 + uq, hb,
                         __ATOMIC_RELAXED, __HIP_MEMORY_SCOPE_AGENT);
    }
    __syncthreads();   // all waves drain vmcnt -> h stores acked at MALL

    // fan-in/fan-out tree barrier, all relaxed, step-indexed (first touch)
    if (tid == 0) {
      const unsigned g = (unsigned)(wg & 15);
      unsigned* gslot = grp + ((size_t)t * 16 + g) * 16;        // 64B-strided
      unsigned old = __hip_atomic_fetch_add(gslot, 1u, __ATOMIC_RELAXED,
                                            __HIP_MEMORY_SCOPE_AGENT);
      if (old == 7u) {   // group complete -> promote to root
        unsigned old2 = __hip_atomic_fetch_add(root + (size_t)t * 16, 1u,
                                               __ATOMIC_RELAXED,
                                               __HIP_MEMORY_SCOPE_AGENT);
        if (old2 == 15u) {   // finishing leader: broadcast release
#pragma unroll
          for (int i = 0; i < 16; ++i)
            __hip_atomic_store(go + ((size_t)t * 16 + i) * 16, 1u,
                               __ATOMIC_RELAXED, __HIP_MEMORY_SCOPE_AGENT);
        }
      }
      int guard = 0;
      while (__hip_atomic_load(go + ((size_t)t * 16 + g) * 16, __ATOMIC_RELAXED,
                               __HIP_MEMORY_SCOPE_AGENT) == 0u) {
        __builtin_amdgcn_s_sleep(1);
        if (++guard > (1 << 22)) break;   // bounded: fail loud, never hang
      }
    }
    __syncthreads();

    xv0 = xn0; xv1 = xn1; xv2 = xn2; xv3 = xn3;
  }

  if (tid < 256) cbuf[(size_t)bq * H_ + J0 + uq] = cstate;
}

// ---------------- host ----------------
extern "C" void kernel_launch(void* const* d_in, const int* in_sizes, int n_in,
                              void* d_out, int out_size, void* d_ws, size_t ws_size,
                              hipStream_t stream) {
  const int*   src = (const int*)d_in[0];
  const float* emb = (const float*)d_in[1];
  const float* Wih = (const float*)d_in[2];
  const float* Whh = (const float*)d_in[3];
  const float* bih = (const float*)d_in[4];
  const float* bhh = (const float*)d_in[5];
  float* out = (float*)d_out;

  // ws: [cbuf 128K][root 32K][grp 512K][go 512K][Wt 8M][hring][xg]
  char* ws = (char*)d_ws;
  float*     cbuf = (float*)ws;                                  // 131072
  unsigned*  root = (unsigned*)(ws + 131072);                    // 32768
  unsigned*  grp  = (unsigned*)(ws + 131072 + 32768);            // 524288
  unsigned*  go   = (unsigned*)(ws + 131072 + 32768 + 524288);   // 524288
  const size_t stateBytes = 131072 + 32768 + 524288 + 524288;    // 1212416
  _Float16*  Wt   = (_Float16*)(ws + stateBytes);                // 8 MB
  const size_t wtBytes = (size_t)G_ * H_ * 2;

  int chunk = 0;
  const int cand[4] = {256, 128, 64, 32};
  for (int ci = 0; ci < 4; ++ci) {
    size_t need = stateBytes + wtBytes + (size_t)(cand[ci] + 1) * (BH_ * 2)
                  + (size_t)cand[ci] * B_ * G_ * 4;
    if (need <= ws_size) { chunk = cand[ci]; break; }
  }
  if (chunk == 0) return;  // fail loud

  unsigned short* hring = (unsigned short*)(ws + stateBytes + wtBytes);
  float* xg = (float*)(ws + stateBytes + wtBytes + (size_t)(chunk + 1) * (BH_ * 2));

  (void)hipMemsetAsync(ws, 0, stateBytes, stream);   // c0 = 0, all counters/go = 0
  (void)hipMemsetAsync(hring, 0, BH_ * 2, stream);   // h0 = 0 (ring slot 0)

  wt_kernel<<<dim3(64, 16), 256, 0, stream>>>(Whh, Wt);

  for (int t0 = 0; t0 < S_; t0 += chunk) {
    dim3 ga(G_ / 128, (chunk * B_) / 128);
    xgates_gemm<<<ga, 256, 0, stream>>>(src, emb, Wih, bih, bhh, xg, t0);

    int nt = chunk;
    void* args[] = {(void*)&Wt, (void*)&xg, (void*)&hring, (void*)&cbuf,
                    (void*)&root, (void*)&grp, (void*)&go, (void*)&out,
                    (void*)&t0, (void*)&nt};
    (void)hipLaunchCooperativeKernel((void*)lstm_mfma, dim3(NWG), dim3(RTHR),
                                     args, 0u, stream);
  }
}